// Round 2
// baseline (1521.432 us; speedup 1.0000x reference)
//
#include <hip/hip_runtime.h>

#define THREADS 256

// ---------------- degree / norm ----------------
__global__ __launch_bounds__(THREADS)
void k_init_deg(int* __restrict__ deg, int N) {
    int i = blockIdx.x * blockDim.x + threadIdx.x;
    if (i < N) deg[i] = 1;  // self loop
}

__global__ __launch_bounds__(THREADS)
void k_count(const int* __restrict__ dst, int E, int* __restrict__ deg) {
    int e = blockIdx.x * blockDim.x + threadIdx.x;
    if (e < E) atomicAdd(&deg[dst[e]], 1);
}

__global__ __launch_bounds__(THREADS)
void k_dinv(const int* __restrict__ deg, float* __restrict__ dinv, int N) {
    int i = blockIdx.x * blockDim.x + threadIdx.x;
    if (i < N) dinv[i] = rsqrtf((float)deg[i]);  // deg >= 1 always
}

// ---------------- dense transforms ----------------
// h[N,32] = x[N,128] @ W[128,32], fp32. 8 rows/block.
__global__ __launch_bounds__(THREADS)
void k_gemm1(const float* __restrict__ x, const float* __restrict__ W,
             float* __restrict__ h, int N) {
    __shared__ float Ws[128 * 32];
    __shared__ float xs[8][128];
    int tid = threadIdx.x;
    for (int j = tid; j < 128 * 32; j += THREADS) Ws[j] = W[j];
    int row0 = blockIdx.x * 8;
    if (row0 + 8 <= N) {
        const float4* xv = reinterpret_cast<const float4*>(x + (size_t)row0 * 128);
        float4 u = xv[tid];              // 256 threads * 16B = 8 rows * 128 floats
        int base = tid * 4;
        int r = base >> 7, k = base & 127;
        xs[r][k + 0] = u.x; xs[r][k + 1] = u.y;
        xs[r][k + 2] = u.z; xs[r][k + 3] = u.w;
    } else {
        for (int j = tid; j < 8 * 128; j += THREADS) {
            int r = j >> 7, k = j & 127;
            int gr = row0 + r;
            xs[r][k] = (gr < N) ? x[(size_t)gr * 128 + k] : 0.f;
        }
    }
    __syncthreads();
    int r = tid >> 5;   // 0..7
    int c = tid & 31;   // 0..31
    int grow = row0 + r;
    if (grow < N) {
        float acc = 0.f;
        #pragma unroll
        for (int k = 0; k < 128; ++k) acc += xs[r][k] * Ws[k * 32 + c];
        h[(size_t)grow * 32 + c] = acc;
    }
}

// hout[N,32] = hin[N,32] @ W[32,32]
__global__ __launch_bounds__(THREADS)
void k_gemm2(const float* __restrict__ hin, const float* __restrict__ W,
             float* __restrict__ hout, int N) {
    __shared__ float Ws[32 * 32];
    __shared__ float xs[8][32];
    int tid = threadIdx.x;
    for (int j = tid; j < 1024; j += THREADS) Ws[j] = W[j];
    int row0 = blockIdx.x * 8;
    for (int j = tid; j < 256; j += THREADS) {
        int r = j >> 5, k = j & 31;
        int gr = row0 + r;
        xs[r][k] = (gr < N) ? hin[(size_t)gr * 32 + k] : 0.f;
    }
    __syncthreads();
    int r = tid >> 5, c = tid & 31;
    int gr = row0 + r;
    if (gr < N) {
        float acc = 0.f;
        #pragma unroll
        for (int k = 0; k < 32; ++k) acc += xs[r][k] * Ws[k * 32 + c];
        hout[(size_t)gr * 32 + c] = acc;
    }
}

// out[N,64] = hin[N,32] @ W[32,64] + b[64]
__global__ __launch_bounds__(THREADS)
void k_out(const float* __restrict__ hin, const float* __restrict__ W,
           const float* __restrict__ b, float* __restrict__ out, int N) {
    __shared__ float Ws[32 * 64];
    __shared__ float bs[64];
    __shared__ float xs[4][32];
    int tid = threadIdx.x;
    for (int j = tid; j < 2048; j += THREADS) Ws[j] = W[j];
    if (tid < 64) bs[tid] = b[tid];
    int row0 = blockIdx.x * 4;
    if (tid < 128) {
        int r = tid >> 5, k = tid & 31;
        int gr = row0 + r;
        xs[r][k] = (gr < N) ? hin[(size_t)gr * 32 + k] : 0.f;
    }
    __syncthreads();
    int r = tid >> 6;   // 0..3
    int c = tid & 63;   // 0..63
    int gr = row0 + r;
    if (gr < N) {
        float acc = bs[c];
        #pragma unroll
        for (int k = 0; k < 32; ++k) acc += xs[r][k] * Ws[k * 64 + c];
        out[(size_t)gr * 64 + c] = acc;
    }
}

// ---------------- aggregation ----------------
// agg[i,:] = h[i,:] * dinv[i]^2   (self-loop term), i over N*32 flat
__global__ __launch_bounds__(THREADS)
void k_selfinit(const float* __restrict__ h, const float* __restrict__ dinv,
                float* __restrict__ agg, int N32) {
    int i = blockIdx.x * blockDim.x + threadIdx.x;
    if (i < N32) {
        float d = dinv[i >> 5];
        agg[i] = h[i] * d * d;
    }
}

// 8 threads per edge; each thread handles 4 contiguous features (float4 gather + 4 atomics)
__global__ __launch_bounds__(THREADS)
void k_edge_agg(const int* __restrict__ src, const int* __restrict__ dst,
                const float* __restrict__ dinv, const float* __restrict__ h,
                float* __restrict__ agg, int E) {
    int gid = blockIdx.x * blockDim.x + threadIdx.x;
    int e = gid >> 3;
    if (e >= E) return;
    int t = gid & 7;
    int s = src[e];
    int d = dst[e];
    float n = dinv[s] * dinv[d];
    const float4 hv = *reinterpret_cast<const float4*>(h + (size_t)s * 32 + t * 4);
    float* ap = agg + (size_t)d * 32 + t * 4;
    atomicAdd(ap + 0, hv.x * n);
    atomicAdd(ap + 1, hv.y * n);
    atomicAdd(ap + 2, hv.z * n);
    atomicAdd(ap + 3, hv.w * n);
}

__global__ __launch_bounds__(THREADS)
void k_bias_relu(float* __restrict__ agg, const float* __restrict__ b, int N32) {
    int i = blockIdx.x * blockDim.x + threadIdx.x;
    if (i < N32) {
        float v = agg[i] + b[i & 31];
        agg[i] = v > 0.f ? v : 0.f;
    }
}

extern "C" void kernel_launch(void* const* d_in, const int* in_sizes, int n_in,
                              void* d_out, int out_size, void* d_ws, size_t ws_size,
                              hipStream_t stream) {
    const float* x  = (const float*)d_in[0];
    const int*   ei = (const int*)d_in[1];
    const float* W1 = (const float*)d_in[2];
    const float* b1 = (const float*)d_in[3];
    const float* W2 = (const float*)d_in[4];
    const float* b2 = (const float*)d_in[5];
    const float* Wo = (const float*)d_in[6];
    const float* bo = (const float*)d_in[7];
    float* out = (float*)d_out;

    const int N = in_sizes[0] / 128;   // 50000
    const int E = in_sizes[1] / 2;     // 1600000
    const int N32 = N * 32;
    const int* src = ei;
    const int* dst = ei + E;

    char* ws = (char*)d_ws;
    size_t off = 0;
    int*   deg  = (int*)(ws + off);   off += ((size_t)N * 4 + 255) & ~(size_t)255;
    float* dinv = (float*)(ws + off); off += ((size_t)N * 4 + 255) & ~(size_t)255;
    float* bufA = (float*)(ws + off); off += ((size_t)N32 * 4 + 255) & ~(size_t)255;
    float* bufB = (float*)(ws + off); off += ((size_t)N32 * 4 + 255) & ~(size_t)255;

    const int gN    = (N + THREADS - 1) / THREADS;
    const int gE    = (E + THREADS - 1) / THREADS;
    const int gN32  = (N32 + THREADS - 1) / THREADS;
    const int gRow8 = (N + 7) / 8;
    const int gRow4 = (N + 3) / 4;
    const int gEdge = (int)(((long long)E * 8 + THREADS - 1) / THREADS);

    // degrees + norm
    k_init_deg<<<gN, THREADS, 0, stream>>>(deg, N);
    k_count<<<gE, THREADS, 0, stream>>>(dst, E, deg);
    k_dinv<<<gN, THREADS, 0, stream>>>(deg, dinv, N);

    // layer 1: transform -> aggregate -> bias+relu
    k_gemm1<<<gRow8, THREADS, 0, stream>>>(x, W1, bufA, N);
    k_selfinit<<<gN32, THREADS, 0, stream>>>(bufA, dinv, bufB, N32);
    k_edge_agg<<<gEdge, THREADS, 0, stream>>>(src, dst, dinv, bufA, bufB, E);
    k_bias_relu<<<gN32, THREADS, 0, stream>>>(bufB, b1, N32);

    // layer 2
    k_gemm2<<<gRow8, THREADS, 0, stream>>>(bufB, W2, bufA, N);
    k_selfinit<<<gN32, THREADS, 0, stream>>>(bufA, dinv, bufB, N32);
    k_edge_agg<<<gEdge, THREADS, 0, stream>>>(src, dst, dinv, bufA, bufB, E);
    k_bias_relu<<<gN32, THREADS, 0, stream>>>(bufB, b2, N32);

    // head
    k_out<<<gRow4, THREADS, 0, stream>>>(bufB, Wo, bo, out, N);
}

// Round 3
// 498.208 us; speedup vs baseline: 3.0538x; 3.0538x over previous
//
#include <hip/hip_runtime.h>

#define THREADS 256
#define SCAN_BLK 1024   // elements per scan block (256 threads x 4)

// ---------------- degree / norm ----------------
__global__ __launch_bounds__(THREADS)
void k_init_deg(int* __restrict__ deg, int N) {
    int i = blockIdx.x * blockDim.x + threadIdx.x;
    if (i < N) deg[i] = 1;  // self loop
}

__global__ __launch_bounds__(THREADS)
void k_count(const int* __restrict__ dst, int E, int* __restrict__ deg) {
    int e = blockIdx.x * blockDim.x + threadIdx.x;
    if (e < E) atomicAdd(&deg[dst[e]], 1);
}

__global__ __launch_bounds__(THREADS)
void k_dinv(const int* __restrict__ deg, float* __restrict__ dinv, int N) {
    int i = blockIdx.x * blockDim.x + threadIdx.x;
    if (i < N) dinv[i] = rsqrtf((float)deg[i]);  // deg >= 1 always
}

// ---------------- exclusive scan of (deg-1) = in-edge counts ----------------
// NOTE: CSR is over real edges only (E entries); self loops handled in k_agg.
// scan1: per-block exclusive scan of cnt[i] = deg[i]-1, write partial rowptr + block sums
__global__ __launch_bounds__(256)
void k_scan1(const int* __restrict__ deg, int* __restrict__ rowptr,
             int* __restrict__ bsum, int N) {
    __shared__ int s[256];
    int b = blockIdx.x, tid = threadIdx.x;
    int base = b * SCAN_BLK + tid * 4;
    int v[4];
    int sum = 0;
    #pragma unroll
    for (int i = 0; i < 4; ++i) {
        int g = base + i;
        v[i] = (g < N) ? (deg[g] - 1) : 0;
        sum += v[i];
    }
    s[tid] = sum;
    __syncthreads();
    for (int off = 1; off < 256; off <<= 1) {
        int val = (tid >= off) ? s[tid - off] : 0;
        __syncthreads();
        s[tid] += val;
        __syncthreads();
    }
    int run = (tid == 0) ? 0 : s[tid - 1];
    if (tid == 255) bsum[b] = s[255];
    #pragma unroll
    for (int i = 0; i < 4; ++i) {
        int g = base + i;
        if (g < N) rowptr[g] = run;
        run += v[i];
    }
}

// scan2: single block scans the block sums (nb <= 64)
__global__ __launch_bounds__(64)
void k_scan2(int* __restrict__ bsum, int nb, int* __restrict__ total) {
    __shared__ int s[64];
    int tid = threadIdx.x;
    s[tid] = (tid < nb) ? bsum[tid] : 0;
    __syncthreads();
    for (int off = 1; off < 64; off <<= 1) {
        int val = (tid >= off) ? s[tid - off] : 0;
        __syncthreads();
        s[tid] += val;
        __syncthreads();
    }
    int excl = (tid == 0) ? 0 : s[tid - 1];
    if (tid < nb) bsum[tid] = excl;
    if (tid == 63) *total = s[63];
}

// scan3: add block offsets; init cursor copy
__global__ __launch_bounds__(256)
void k_scan3(int* __restrict__ rowptr, const int* __restrict__ bsum,
             int* __restrict__ cursor, int N) {
    int i = blockIdx.x * blockDim.x + threadIdx.x;
    if (i < N) {
        int v = rowptr[i] + bsum[i >> 10];
        rowptr[i] = v;
        cursor[i] = v;
    }
}

// fill CSR: for each edge, place src id into dst's bucket
__global__ __launch_bounds__(THREADS)
void k_fill(const int* __restrict__ src, const int* __restrict__ dst,
            int* __restrict__ cursor, int* __restrict__ csr_src, int E) {
    int e = blockIdx.x * blockDim.x + threadIdx.x;
    if (e < E) {
        int d = dst[e];
        int pos = atomicAdd(&cursor[d], 1);
        csr_src[pos] = src[e];
    }
}

// ---------------- dense transforms ----------------
// h[N,32] = x[N,128] @ W[128,32], fp32. 8 rows/block.
__global__ __launch_bounds__(THREADS)
void k_gemm1(const float* __restrict__ x, const float* __restrict__ W,
             float* __restrict__ h, int N) {
    __shared__ float Ws[128 * 32];
    __shared__ float xs[8][128];
    int tid = threadIdx.x;
    for (int j = tid; j < 128 * 32; j += THREADS) Ws[j] = W[j];
    int row0 = blockIdx.x * 8;
    if (row0 + 8 <= N) {
        const float4* xv = reinterpret_cast<const float4*>(x + (size_t)row0 * 128);
        float4 u = xv[tid];
        int base = tid * 4;
        int r = base >> 7, k = base & 127;
        xs[r][k + 0] = u.x; xs[r][k + 1] = u.y;
        xs[r][k + 2] = u.z; xs[r][k + 3] = u.w;
    } else {
        for (int j = tid; j < 8 * 128; j += THREADS) {
            int r = j >> 7, k = j & 127;
            int gr = row0 + r;
            xs[r][k] = (gr < N) ? x[(size_t)gr * 128 + k] : 0.f;
        }
    }
    __syncthreads();
    int r = tid >> 5, c = tid & 31;
    int grow = row0 + r;
    if (grow < N) {
        float acc = 0.f;
        #pragma unroll
        for (int k = 0; k < 128; ++k) acc += xs[r][k] * Ws[k * 32 + c];
        h[(size_t)grow * 32 + c] = acc;
    }
}

// hout[N,32] = hin[N,32] @ W[32,32]
__global__ __launch_bounds__(THREADS)
void k_gemm2(const float* __restrict__ hin, const float* __restrict__ W,
             float* __restrict__ hout, int N) {
    __shared__ float Ws[32 * 32];
    __shared__ float xs[8][32];
    int tid = threadIdx.x;
    for (int j = tid; j < 1024; j += THREADS) Ws[j] = W[j];
    int row0 = blockIdx.x * 8;
    for (int j = tid; j < 256; j += THREADS) {
        int r = j >> 5, k = j & 31;
        int gr = row0 + r;
        xs[r][k] = (gr < N) ? hin[(size_t)gr * 32 + k] : 0.f;
    }
    __syncthreads();
    int r = tid >> 5, c = tid & 31;
    int gr = row0 + r;
    if (gr < N) {
        float acc = 0.f;
        #pragma unroll
        for (int k = 0; k < 32; ++k) acc += xs[r][k] * Ws[k * 32 + c];
        hout[(size_t)gr * 32 + c] = acc;
    }
}

// out[N,64] = hin[N,32] @ W[32,64] + b[64]
__global__ __launch_bounds__(THREADS)
void k_out(const float* __restrict__ hin, const float* __restrict__ W,
           const float* __restrict__ b, float* __restrict__ out, int N) {
    __shared__ float Ws[32 * 64];
    __shared__ float bs[64];
    __shared__ float xs[4][32];
    int tid = threadIdx.x;
    for (int j = tid; j < 2048; j += THREADS) Ws[j] = W[j];
    if (tid < 64) bs[tid] = b[tid];
    int row0 = blockIdx.x * 4;
    if (tid < 128) {
        int r = tid >> 5, k = tid & 31;
        int gr = row0 + r;
        xs[r][k] = (gr < N) ? hin[(size_t)gr * 32 + k] : 0.f;
    }
    __syncthreads();
    int r = tid >> 6, c = tid & 63;
    int gr = row0 + r;
    if (gr < N) {
        float acc = bs[c];
        #pragma unroll
        for (int k = 0; k < 32; ++k) acc += xs[r][k] * Ws[k * 64 + c];
        out[(size_t)gr * 64 + c] = acc;
    }
}

// ---------------- aggregation (CSR gather, fused self-loop + bias + ReLU) ----
// 32 lanes per node (lane = feature), 8 nodes per block.
__global__ __launch_bounds__(THREADS)
void k_agg(const float* __restrict__ h, const int* __restrict__ rowptr,
           const int* __restrict__ csr_src, const float* __restrict__ dinv,
           const float* __restrict__ b, float* __restrict__ out, int N) {
    int tid = threadIdx.x;
    int node = blockIdx.x * 8 + (tid >> 5);
    if (node >= N) return;
    int t = tid & 31;
    float dd = dinv[node];
    // self loop: h[d] * dinv[d]^2  (one dd factored out, applied at the end)
    float acc = h[(size_t)node * 32 + t] * dd;
    int beg = rowptr[node];
    int end = rowptr[node + 1];
    for (int j = beg; j < end; ++j) {
        int s = csr_src[j];            // broadcast within half-wave
        float w = dinv[s];             // broadcast
        acc += h[(size_t)s * 32 + t] * w;   // coalesced 128B row gather
    }
    float v = acc * dd + b[t];
    out[(size_t)node * 32 + t] = v > 0.f ? v : 0.f;
}

extern "C" void kernel_launch(void* const* d_in, const int* in_sizes, int n_in,
                              void* d_out, int out_size, void* d_ws, size_t ws_size,
                              hipStream_t stream) {
    const float* x  = (const float*)d_in[0];
    const int*   ei = (const int*)d_in[1];
    const float* W1 = (const float*)d_in[2];
    const float* b1 = (const float*)d_in[3];
    const float* W2 = (const float*)d_in[4];
    const float* b2 = (const float*)d_in[5];
    const float* Wo = (const float*)d_in[6];
    const float* bo = (const float*)d_in[7];
    float* out = (float*)d_out;

    const int N = in_sizes[0] / 128;   // 50000
    const int E = in_sizes[1] / 2;     // 1600000
    const int N32 = N * 32;
    const int* src = ei;
    const int* dst = ei + E;

    char* ws = (char*)d_ws;
    size_t off = 0;
    auto alloc = [&](size_t bytes) {
        void* p = ws + off;
        off += (bytes + 255) & ~(size_t)255;
        return p;
    };
    int*   deg     = (int*)  alloc((size_t)N * 4);
    float* dinv    = (float*)alloc((size_t)N * 4);
    int*   rowptr  = (int*)  alloc((size_t)(N + 1) * 4);
    int*   cursor  = (int*)  alloc((size_t)N * 4);
    int*   bsum    = (int*)  alloc(64 * 4);
    int*   csr_src = (int*)  alloc((size_t)E * 4);
    float* bufA    = (float*)alloc((size_t)N32 * 4);
    float* bufB    = (float*)alloc((size_t)N32 * 4);

    const int gN    = (N + THREADS - 1) / THREADS;
    const int gE    = (E + THREADS - 1) / THREADS;
    const int gRow8 = (N + 7) / 8;
    const int gRow4 = (N + 3) / 4;
    const int nScanBlk = (N + SCAN_BLK - 1) / SCAN_BLK;   // 49

    // ---- CSR build (once, reused by both layers) ----
    k_init_deg<<<gN, THREADS, 0, stream>>>(deg, N);
    k_count<<<gE, THREADS, 0, stream>>>(dst, E, deg);
    k_dinv<<<gN, THREADS, 0, stream>>>(deg, dinv, N);
    k_scan1<<<nScanBlk, 256, 0, stream>>>(deg, rowptr, bsum, N);
    k_scan2<<<1, 64, 0, stream>>>(bsum, nScanBlk, rowptr + N);
    k_scan3<<<gN, THREADS, 0, stream>>>(rowptr, bsum, cursor, N);
    k_fill<<<gE, THREADS, 0, stream>>>(src, dst, cursor, csr_src, E);

    // ---- layer 1 ----
    k_gemm1<<<gRow8, THREADS, 0, stream>>>(x, W1, bufA, N);
    k_agg<<<gRow8, THREADS, 0, stream>>>(bufA, rowptr, csr_src, dinv, b1, bufB, N);

    // ---- layer 2 ----
    k_gemm2<<<gRow8, THREADS, 0, stream>>>(bufB, W2, bufA, N);
    k_agg<<<gRow8, THREADS, 0, stream>>>(bufA, rowptr, csr_src, dinv, b2, bufB, N);

    // ---- head ----
    k_out<<<gRow4, THREADS, 0, stream>>>(bufB, Wo, bo, out, N);
}

// Round 4
// 471.620 us; speedup vs baseline: 3.2260x; 1.0564x over previous
//
#include <hip/hip_runtime.h>

#define THREADS 256
#define SCAN_BLK 1024   // elements per scan block (256 threads x 4)

// ---------------- degree ----------------
__global__ __launch_bounds__(THREADS)
void k_init_deg(int* __restrict__ deg, int N) {
    int i = blockIdx.x * blockDim.x + threadIdx.x;
    if (i < N) deg[i] = 1;  // self loop
}

__global__ __launch_bounds__(THREADS)
void k_count(const int* __restrict__ dst, int E, int* __restrict__ deg) {
    int e0 = (blockIdx.x * blockDim.x + threadIdx.x) * 4;
    if (e0 + 3 < E) {
        int4 d4 = *reinterpret_cast<const int4*>(dst + e0);
        atomicAdd(&deg[d4.x], 1);
        atomicAdd(&deg[d4.y], 1);
        atomicAdd(&deg[d4.z], 1);
        atomicAdd(&deg[d4.w], 1);
    } else {
        for (int e = e0; e < E; ++e) atomicAdd(&deg[dst[e]], 1);
    }
}

// ---------------- scan of (deg-1) + dinv ----------------
__global__ __launch_bounds__(256)
void k_scan1(const int* __restrict__ deg, int* __restrict__ rowptr,
             int* __restrict__ bsum, float* __restrict__ dinv, int N) {
    __shared__ int s[256];
    int b = blockIdx.x, tid = threadIdx.x;
    int base = b * SCAN_BLK + tid * 4;
    int v[4];
    int sum = 0;
    #pragma unroll
    for (int i = 0; i < 4; ++i) {
        int g = base + i;
        int dg = (g < N) ? deg[g] : 1;
        if (g < N) dinv[g] = rsqrtf((float)dg);
        v[i] = dg - 1;
        sum += v[i];
    }
    s[tid] = sum;
    __syncthreads();
    for (int off = 1; off < 256; off <<= 1) {
        int val = (tid >= off) ? s[tid - off] : 0;
        __syncthreads();
        s[tid] += val;
        __syncthreads();
    }
    int run = (tid == 0) ? 0 : s[tid - 1];
    if (tid == 255) bsum[b] = s[255];
    #pragma unroll
    for (int i = 0; i < 4; ++i) {
        int g = base + i;
        if (g < N) rowptr[g] = run;
        run += v[i];
    }
}

__global__ __launch_bounds__(64)
void k_scan2(int* __restrict__ bsum, int nb, int* __restrict__ total) {
    __shared__ int s[64];
    int tid = threadIdx.x;
    s[tid] = (tid < nb) ? bsum[tid] : 0;
    __syncthreads();
    for (int off = 1; off < 64; off <<= 1) {
        int val = (tid >= off) ? s[tid - off] : 0;
        __syncthreads();
        s[tid] += val;
        __syncthreads();
    }
    int excl = (tid == 0) ? 0 : s[tid - 1];
    if (tid < nb) bsum[tid] = excl;
    if (tid == 63) *total = s[63];
}

__global__ __launch_bounds__(256)
void k_scan3(int* __restrict__ rowptr, const int* __restrict__ bsum,
             int* __restrict__ cursor, int N) {
    int i = blockIdx.x * blockDim.x + threadIdx.x;
    if (i < N) {
        int v = rowptr[i] + bsum[i >> 10];
        rowptr[i] = v;
        cursor[i] = v;
    }
}

// fill CSR (ushort payload: N < 65536)
__global__ __launch_bounds__(THREADS)
void k_fill(const int* __restrict__ src, const int* __restrict__ dst,
            int* __restrict__ cursor, unsigned short* __restrict__ csr, int E) {
    int e0 = (blockIdx.x * blockDim.x + threadIdx.x) * 4;
    if (e0 + 3 < E) {
        int4 d4 = *reinterpret_cast<const int4*>(dst + e0);
        int4 s4 = *reinterpret_cast<const int4*>(src + e0);
        int p0 = atomicAdd(&cursor[d4.x], 1);
        int p1 = atomicAdd(&cursor[d4.y], 1);
        int p2 = atomicAdd(&cursor[d4.z], 1);
        int p3 = atomicAdd(&cursor[d4.w], 1);
        csr[p0] = (unsigned short)s4.x;
        csr[p1] = (unsigned short)s4.y;
        csr[p2] = (unsigned short)s4.z;
        csr[p3] = (unsigned short)s4.w;
    } else {
        for (int e = e0; e < E; ++e) {
            int pos = atomicAdd(&cursor[dst[e]], 1);
            csr[pos] = (unsigned short)src[e];
        }
    }
}

// ---------------- dense transforms (epilogue: scale row by dinv) ----------
// hp[N,32] = (x[N,128] @ W[128,32]) * dinv[row]
__global__ __launch_bounds__(THREADS)
void k_gemm1(const float* __restrict__ x, const float* __restrict__ W,
             const float* __restrict__ dinv, float* __restrict__ hp, int N) {
    __shared__ float Ws[128 * 32];
    __shared__ float xs[8][128];
    int tid = threadIdx.x;
    for (int j = tid; j < 128 * 32; j += THREADS) Ws[j] = W[j];
    int row0 = blockIdx.x * 8;
    if (row0 + 8 <= N) {
        const float4* xv = reinterpret_cast<const float4*>(x + (size_t)row0 * 128);
        float4 u = xv[tid];
        int base = tid * 4;
        int r = base >> 7, k = base & 127;
        xs[r][k + 0] = u.x; xs[r][k + 1] = u.y;
        xs[r][k + 2] = u.z; xs[r][k + 3] = u.w;
    } else {
        for (int j = tid; j < 8 * 128; j += THREADS) {
            int r = j >> 7, k = j & 127;
            int gr = row0 + r;
            xs[r][k] = (gr < N) ? x[(size_t)gr * 128 + k] : 0.f;
        }
    }
    __syncthreads();
    int r = tid >> 5, c = tid & 31;
    int grow = row0 + r;
    if (grow < N) {
        float acc = 0.f;
        #pragma unroll
        for (int k = 0; k < 128; ++k) acc += xs[r][k] * Ws[k * 32 + c];
        hp[(size_t)grow * 32 + c] = acc * dinv[grow];
    }
}

// hp[N,32] = (hin[N,32] @ W[32,32]) * dinv[row]
__global__ __launch_bounds__(THREADS)
void k_gemm2(const float* __restrict__ hin, const float* __restrict__ W,
             const float* __restrict__ dinv, float* __restrict__ hp, int N) {
    __shared__ float Ws[32 * 32];
    __shared__ float xs[8][32];
    int tid = threadIdx.x;
    for (int j = tid; j < 1024; j += THREADS) Ws[j] = W[j];
    int row0 = blockIdx.x * 8;
    for (int j = tid; j < 256; j += THREADS) {
        int r = j >> 5, k = j & 31;
        int gr = row0 + r;
        xs[r][k] = (gr < N) ? hin[(size_t)gr * 32 + k] : 0.f;
    }
    __syncthreads();
    int r = tid >> 5, c = tid & 31;
    int gr = row0 + r;
    if (gr < N) {
        float acc = 0.f;
        #pragma unroll
        for (int k = 0; k < 32; ++k) acc += xs[r][k] * Ws[k * 32 + c];
        hp[(size_t)gr * 32 + c] = acc * dinv[gr];
    }
}

// out[N,64] = hin[N,32] @ W[32,64] + b[64]
__global__ __launch_bounds__(THREADS)
void k_out(const float* __restrict__ hin, const float* __restrict__ W,
           const float* __restrict__ b, float* __restrict__ out, int N) {
    __shared__ float Ws[32 * 64];
    __shared__ float bs[64];
    __shared__ float xs[4][32];
    int tid = threadIdx.x;
    for (int j = tid; j < 2048; j += THREADS) Ws[j] = W[j];
    if (tid < 64) bs[tid] = b[tid];
    int row0 = blockIdx.x * 4;
    if (tid < 128) {
        int r = tid >> 5, k = tid & 31;
        int gr = row0 + r;
        xs[r][k] = (gr < N) ? hin[(size_t)gr * 32 + k] : 0.f;
    }
    __syncthreads();
    int r = tid >> 6, c = tid & 63;
    int gr = row0 + r;
    if (gr < N) {
        float acc = bs[c];
        #pragma unroll
        for (int k = 0; k < 32; ++k) acc += xs[r][k] * Ws[k * 64 + c];
        out[(size_t)gr * 64 + c] = acc;
    }
}

// ---------------- aggregation (CSR gather, shfl-broadcast, fused epilogue) --
// 32 lanes per node (lane = feature), 8 nodes per block.
// hp rows are pre-scaled by dinv[row]; self loop = hp[node]; final *dinv[node]+b, relu.
__global__ __launch_bounds__(THREADS)
void k_agg(const float* __restrict__ hp, const int* __restrict__ rowptr,
           const unsigned short* __restrict__ csr, const float* __restrict__ dinv,
           const float* __restrict__ b, float* __restrict__ out, int N) {
    int tid = threadIdx.x;
    int node = blockIdx.x * 8 + (tid >> 5);
    if (node >= N) return;
    int t = tid & 31;
    float acc = hp[(size_t)node * 32 + t];   // self loop
    int beg = rowptr[node];
    int end = rowptr[node + 1];
    int c = beg;
    // full chunks of 32 edges: one coalesced csr read + 32 broadcast gathers
    for (; c + 32 <= end; c += 32) {
        int sv = (int)csr[c + t];
        #pragma unroll
        for (int jj = 0; jj < 32; ++jj) {
            int s = __shfl(sv, jj, 32);
            acc += hp[(size_t)s * 32 + t];
        }
    }
    if (c < end) {
        int idx = c + t;
        int sv = (idx < end) ? (int)csr[idx] : 0;
        int m = end - c;
        for (int jj = 0; jj < m; ++jj) {
            int s = __shfl(sv, jj, 32);
            acc += hp[(size_t)s * 32 + t];
        }
    }
    float v = acc * dinv[node] + b[t];
    out[(size_t)node * 32 + t] = v > 0.f ? v : 0.f;
}

extern "C" void kernel_launch(void* const* d_in, const int* in_sizes, int n_in,
                              void* d_out, int out_size, void* d_ws, size_t ws_size,
                              hipStream_t stream) {
    const float* x  = (const float*)d_in[0];
    const int*   ei = (const int*)d_in[1];
    const float* W1 = (const float*)d_in[2];
    const float* b1 = (const float*)d_in[3];
    const float* W2 = (const float*)d_in[4];
    const float* b2 = (const float*)d_in[5];
    const float* Wo = (const float*)d_in[6];
    const float* bo = (const float*)d_in[7];
    float* out = (float*)d_out;

    const int N = in_sizes[0] / 128;   // 50000
    const int E = in_sizes[1] / 2;     // 1600000
    const int N32 = N * 32;
    const int* src = ei;
    const int* dst = ei + E;

    char* ws = (char*)d_ws;
    size_t off = 0;
    auto alloc = [&](size_t bytes) {
        void* p = ws + off;
        off += (bytes + 255) & ~(size_t)255;
        return p;
    };
    int*            deg     = (int*)           alloc((size_t)N * 4);
    float*          dinv    = (float*)         alloc((size_t)N * 4);
    int*            rowptr  = (int*)           alloc((size_t)(N + 1) * 4);
    int*            cursor  = (int*)           alloc((size_t)N * 4);
    int*            bsum    = (int*)           alloc(64 * 4);
    unsigned short* csr     = (unsigned short*)alloc((size_t)E * 2);
    float*          bufA    = (float*)         alloc((size_t)N32 * 4);
    float*          bufB    = (float*)         alloc((size_t)N32 * 4);

    const int gN    = (N + THREADS - 1) / THREADS;
    const int gE4   = (int)(((long long)E + 4LL * THREADS - 1) / (4LL * THREADS));
    const int gRow8 = (N + 7) / 8;
    const int gRow4 = (N + 3) / 4;
    const int nScanBlk = (N + SCAN_BLK - 1) / SCAN_BLK;   // 49

    // ---- CSR build (once, reused by both layers) ----
    k_init_deg<<<gN, THREADS, 0, stream>>>(deg, N);
    k_count<<<gE4, THREADS, 0, stream>>>(dst, E, deg);
    k_scan1<<<nScanBlk, 256, 0, stream>>>(deg, rowptr, bsum, dinv, N);
    k_scan2<<<1, 64, 0, stream>>>(bsum, nScanBlk, rowptr + N);
    k_scan3<<<gN, THREADS, 0, stream>>>(rowptr, bsum, cursor, N);
    k_fill<<<gE4, THREADS, 0, stream>>>(src, dst, cursor, csr, E);

    // ---- layer 1 ----
    k_gemm1<<<gRow8, THREADS, 0, stream>>>(x, W1, dinv, bufA, N);
    k_agg<<<gRow8, THREADS, 0, stream>>>(bufA, rowptr, csr, dinv, b1, bufB, N);

    // ---- layer 2 ----
    k_gemm2<<<gRow8, THREADS, 0, stream>>>(bufB, W2, dinv, bufA, N);
    k_agg<<<gRow8, THREADS, 0, stream>>>(bufA, rowptr, csr, dinv, b2, bufB, N);

    // ---- head ----
    k_out<<<gRow4, THREADS, 0, stream>>>(bufB, Wo, bo, out, N);
}

// Round 5
// 320.555 us; speedup vs baseline: 4.7462x; 1.4713x over previous
//
#include <hip/hip_runtime.h>

#define THREADS 256
#define CHUNK 4096   // edges per k_hist / k_binA block

// ---------------- CSR build: counting sort by dst>>8, then per-bucket -------
__global__ __launch_bounds__(256)
void k_zero(int* __restrict__ bcnt) { bcnt[threadIdx.x] = 0; }

// histogram of dst>>8 over 256 buckets
__global__ __launch_bounds__(256)
void k_hist(const int* __restrict__ dst, int E, int* __restrict__ bcnt) {
    __shared__ int h[256];
    int tid = threadIdx.x;
    h[tid] = 0;
    __syncthreads();
    int base = blockIdx.x * CHUNK;
    #pragma unroll
    for (int i = 0; i < 4; ++i) {
        int e = base + i * 1024 + tid * 4;
        if (e + 3 < E) {
            int4 d4 = *reinterpret_cast<const int4*>(dst + e);
            atomicAdd(&h[d4.x >> 8], 1);
            atomicAdd(&h[d4.y >> 8], 1);
            atomicAdd(&h[d4.z >> 8], 1);
            atomicAdd(&h[d4.w >> 8], 1);
        } else {
            for (int k = e; k < E && k < e + 4; ++k) atomicAdd(&h[dst[k] >> 8], 1);
        }
    }
    __syncthreads();
    if (h[tid]) atomicAdd(&bcnt[tid], h[tid]);
}

// single block: bbase = exclusive scan of bcnt; cursor = copy
__global__ __launch_bounds__(256)
void k_bscan(const int* __restrict__ bcnt, int* __restrict__ bbase, int* __restrict__ cursor) {
    __shared__ int s[256];
    int tid = threadIdx.x;
    s[tid] = bcnt[tid];
    __syncthreads();
    for (int off = 1; off < 256; off <<= 1) {
        int v = (tid >= off) ? s[tid - off] : 0;
        __syncthreads();
        s[tid] += v;
        __syncthreads();
    }
    int excl = (tid == 0) ? 0 : s[tid - 1];
    bbase[tid] = excl;
    cursor[tid] = excl;
}

// bin edges (packed dst<<16|src) into bucket-grouped runs; coalesced writes
__global__ __launch_bounds__(256)
void k_binA(const int* __restrict__ src, const int* __restrict__ dst,
            int* __restrict__ cursor, unsigned int* __restrict__ binned, int E) {
    __shared__ int h[256];
    __shared__ int lbase[256];
    __shared__ int lcur[256];
    __shared__ int gbase[256];
    __shared__ unsigned int stage[CHUNK];
    int tid = threadIdx.x;
    h[tid] = 0;
    __syncthreads();
    int base = blockIdx.x * CHUNK;
    unsigned int pk[16];
    unsigned int mask = 0;
    #pragma unroll
    for (int i = 0; i < 4; ++i) {
        int e = base + i * 1024 + tid * 4;
        if (e + 3 < E) {
            int4 d4 = *reinterpret_cast<const int4*>(dst + e);
            int4 s4 = *reinterpret_cast<const int4*>(src + e);
            pk[i*4+0] = ((unsigned)d4.x << 16) | (unsigned)s4.x; atomicAdd(&h[d4.x >> 8], 1);
            pk[i*4+1] = ((unsigned)d4.y << 16) | (unsigned)s4.y; atomicAdd(&h[d4.y >> 8], 1);
            pk[i*4+2] = ((unsigned)d4.z << 16) | (unsigned)s4.z; atomicAdd(&h[d4.z >> 8], 1);
            pk[i*4+3] = ((unsigned)d4.w << 16) | (unsigned)s4.w; atomicAdd(&h[d4.w >> 8], 1);
            mask |= 0xFu << (i * 4);
        } else {
            for (int j = 0; j < 4; ++j) {
                int k = e + j;
                if (k < E) {
                    int d = dst[k], s = src[k];
                    pk[i*4+j] = ((unsigned)d << 16) | (unsigned)s;
                    atomicAdd(&h[d >> 8], 1);
                    mask |= 1u << (i * 4 + j);
                }
            }
        }
    }
    __syncthreads();
    // inclusive scan of h
    for (int off = 1; off < 256; off <<= 1) {
        int v = (tid >= off) ? h[tid - off] : 0;
        __syncthreads();
        h[tid] += v;
        __syncthreads();
    }
    int incl = h[tid];
    int excl = (tid == 0) ? 0 : h[tid - 1];
    int cntb = incl - excl;
    lbase[tid] = excl;
    lcur[tid] = excl;
    gbase[tid] = cntb ? atomicAdd(&cursor[tid], cntb) : 0;
    __syncthreads();
    int nvalid = h[255];
    #pragma unroll
    for (int i = 0; i < 16; ++i) {
        if (mask & (1u << i)) {
            int b = pk[i] >> 24;
            int p = atomicAdd(&lcur[b], 1);
            stage[p] = pk[i];
        }
    }
    __syncthreads();
    for (int i = tid; i < nvalid; i += 256) {
        unsigned int v = stage[i];
        int b = v >> 24;
        binned[gbase[b] + (i - lbase[b])] = v;
    }
}

// one block per bucket (256 nodes): per-node count, scan -> rowptr/dinv,
// then scatter src ids into the block-OWNED csr region.
__global__ __launch_bounds__(256)
void k_binB(const unsigned int* __restrict__ binned, const int* __restrict__ bbase,
            int* __restrict__ rowptr, float* __restrict__ dinv,
            unsigned short* __restrict__ csr, int N, int E) {
    __shared__ int cnt[256];
    __shared__ int lcur[256];
    int tid = threadIdx.x;
    int b = blockIdx.x;
    int bb0 = bbase[b];
    int bb1 = bbase[b + 1];   // buckets beyond nbuckets hold E (scan of zeros)
    cnt[tid] = 0;
    __syncthreads();
    for (int i = bb0 + tid; i < bb1; i += 256) {
        unsigned int v = binned[i];
        atomicAdd(&cnt[(v >> 16) & 255], 1);
    }
    __syncthreads();
    int myc = cnt[tid];
    __syncthreads();
    for (int off = 1; off < 256; off <<= 1) {
        int v = (tid >= off) ? cnt[tid - off] : 0;
        __syncthreads();
        cnt[tid] += v;
        __syncthreads();
    }
    int excl = (tid == 0) ? 0 : cnt[tid - 1];
    int node = (b << 8) + tid;
    if (node < N) {
        rowptr[node] = bb0 + excl;
        dinv[node] = rsqrtf((float)(myc + 1));   // +1 self loop
    }
    if (b == 0 && tid == 0) rowptr[N] = E;
    lcur[tid] = excl;
    __syncthreads();
    for (int i = bb0 + tid; i < bb1; i += 256) {
        unsigned int v = binned[i];
        int dl = (v >> 16) & 255;
        int p = atomicAdd(&lcur[dl], 1);
        csr[bb0 + p] = (unsigned short)(v & 0xFFFFu);
    }
}

// ---------------- dense transforms (epilogue: scale row by dinv) ----------
__global__ __launch_bounds__(THREADS)
void k_gemm1(const float* __restrict__ x, const float* __restrict__ W,
             const float* __restrict__ dinv, float* __restrict__ hp, int N) {
    __shared__ float Ws[128 * 32];
    __shared__ float xs[8][128];
    int tid = threadIdx.x;
    for (int j = tid; j < 128 * 32; j += THREADS) Ws[j] = W[j];
    int row0 = blockIdx.x * 8;
    if (row0 + 8 <= N) {
        const float4* xv = reinterpret_cast<const float4*>(x + (size_t)row0 * 128);
        float4 u = xv[tid];
        int base = tid * 4;
        int r = base >> 7, k = base & 127;
        xs[r][k + 0] = u.x; xs[r][k + 1] = u.y;
        xs[r][k + 2] = u.z; xs[r][k + 3] = u.w;
    } else {
        for (int j = tid; j < 8 * 128; j += THREADS) {
            int r = j >> 7, k = j & 127;
            int gr = row0 + r;
            xs[r][k] = (gr < N) ? x[(size_t)gr * 128 + k] : 0.f;
        }
    }
    __syncthreads();
    int r = tid >> 5, c = tid & 31;
    int grow = row0 + r;
    if (grow < N) {
        float acc = 0.f;
        #pragma unroll
        for (int k = 0; k < 128; ++k) acc += xs[r][k] * Ws[k * 32 + c];
        hp[(size_t)grow * 32 + c] = acc * dinv[grow];
    }
}

__global__ __launch_bounds__(THREADS)
void k_gemm2(const float* __restrict__ hin, const float* __restrict__ W,
             const float* __restrict__ dinv, float* __restrict__ hp, int N) {
    __shared__ float Ws[32 * 32];
    __shared__ float xs[8][32];
    int tid = threadIdx.x;
    for (int j = tid; j < 1024; j += THREADS) Ws[j] = W[j];
    int row0 = blockIdx.x * 8;
    for (int j = tid; j < 256; j += THREADS) {
        int r = j >> 5, k = j & 31;
        int gr = row0 + r;
        xs[r][k] = (gr < N) ? hin[(size_t)gr * 32 + k] : 0.f;
    }
    __syncthreads();
    int r = tid >> 5, c = tid & 31;
    int gr = row0 + r;
    if (gr < N) {
        float acc = 0.f;
        #pragma unroll
        for (int k = 0; k < 32; ++k) acc += xs[r][k] * Ws[k * 32 + c];
        hp[(size_t)gr * 32 + c] = acc * dinv[gr];
    }
}

__global__ __launch_bounds__(THREADS)
void k_out(const float* __restrict__ hin, const float* __restrict__ W,
           const float* __restrict__ b, float* __restrict__ out, int N) {
    __shared__ float Ws[32 * 64];
    __shared__ float bs[64];
    __shared__ float xs[4][32];
    int tid = threadIdx.x;
    for (int j = tid; j < 2048; j += THREADS) Ws[j] = W[j];
    if (tid < 64) bs[tid] = b[tid];
    int row0 = blockIdx.x * 4;
    if (tid < 128) {
        int r = tid >> 5, k = tid & 31;
        int gr = row0 + r;
        xs[r][k] = (gr < N) ? hin[(size_t)gr * 32 + k] : 0.f;
    }
    __syncthreads();
    int r = tid >> 6, c = tid & 63;
    int gr = row0 + r;
    if (gr < N) {
        float acc = bs[c];
        #pragma unroll
        for (int k = 0; k < 32; ++k) acc += xs[r][k] * Ws[k * 64 + c];
        out[(size_t)gr * 64 + c] = acc;
    }
}

// ---------------- aggregation (CSR gather, shfl-broadcast, fused epilogue) --
__global__ __launch_bounds__(THREADS)
void k_agg(const float* __restrict__ hp, const int* __restrict__ rowptr,
           const unsigned short* __restrict__ csr, const float* __restrict__ dinv,
           const float* __restrict__ b, float* __restrict__ out, int N) {
    int tid = threadIdx.x;
    int node = blockIdx.x * 8 + (tid >> 5);
    if (node >= N) return;
    int t = tid & 31;
    float acc = hp[(size_t)node * 32 + t];   // self loop (pre-scaled)
    int beg = rowptr[node];
    int end = rowptr[node + 1];
    int c = beg;
    for (; c + 32 <= end; c += 32) {
        int sv = (int)csr[c + t];
        #pragma unroll
        for (int jj = 0; jj < 32; ++jj) {
            int s = __shfl(sv, jj, 32);
            acc += hp[(size_t)s * 32 + t];
        }
    }
    if (c < end) {
        int idx = c + t;
        int sv = (idx < end) ? (int)csr[idx] : 0;
        int m = end - c;
        for (int jj = 0; jj < m; ++jj) {
            int s = __shfl(sv, jj, 32);
            acc += hp[(size_t)s * 32 + t];
        }
    }
    float v = acc * dinv[node] + b[t];
    out[(size_t)node * 32 + t] = v > 0.f ? v : 0.f;
}

extern "C" void kernel_launch(void* const* d_in, const int* in_sizes, int n_in,
                              void* d_out, int out_size, void* d_ws, size_t ws_size,
                              hipStream_t stream) {
    const float* x  = (const float*)d_in[0];
    const int*   ei = (const int*)d_in[1];
    const float* W1 = (const float*)d_in[2];
    const float* b1 = (const float*)d_in[3];
    const float* W2 = (const float*)d_in[4];
    const float* b2 = (const float*)d_in[5];
    const float* Wo = (const float*)d_in[6];
    const float* bo = (const float*)d_in[7];
    float* out = (float*)d_out;

    const int N = in_sizes[0] / 128;   // 50000
    const int E = in_sizes[1] / 2;     // 1600000
    const int N32 = N * 32;
    const int* src = ei;
    const int* dst = ei + E;

    char* ws = (char*)d_ws;
    size_t off = 0;
    auto alloc = [&](size_t bytes) {
        void* p = ws + off;
        off += (bytes + 255) & ~(size_t)255;
        return p;
    };
    int*            bcnt   = (int*)           alloc(256 * 4);
    int*            bbase  = (int*)           alloc(256 * 4);
    int*            cursor = (int*)           alloc(256 * 4);
    unsigned int*   binned = (unsigned int*)  alloc((size_t)E * 4);
    int*            rowptr = (int*)           alloc((size_t)(N + 1) * 4);
    float*          dinv   = (float*)         alloc((size_t)N * 4);
    unsigned short* csr    = (unsigned short*)alloc((size_t)E * 2);
    float*          bufA   = (float*)         alloc((size_t)N32 * 4);
    float*          bufB   = (float*)         alloc((size_t)N32 * 4);

    const int gRow8  = (N + 7) / 8;
    const int gRow4  = (N + 3) / 4;
    const int gChunk = (E + CHUNK - 1) / CHUNK;      // 391
    const int nBuckets = (N + 255) >> 8;             // 196

    // ---- CSR build (counting sort by dst>>8; block-owned scatter) ----
    k_zero<<<1, 256, 0, stream>>>(bcnt);
    k_hist<<<gChunk, 256, 0, stream>>>(dst, E, bcnt);
    k_bscan<<<1, 256, 0, stream>>>(bcnt, bbase, cursor);
    k_binA<<<gChunk, 256, 0, stream>>>(src, dst, cursor, binned, E);
    k_binB<<<nBuckets, 256, 0, stream>>>(binned, bbase, rowptr, dinv, csr, N, E);

    // ---- layer 1 ----
    k_gemm1<<<gRow8, THREADS, 0, stream>>>(x, W1, dinv, bufA, N);
    k_agg<<<gRow8, THREADS, 0, stream>>>(bufA, rowptr, csr, dinv, b1, bufB, N);

    // ---- layer 2 ----
    k_gemm2<<<gRow8, THREADS, 0, stream>>>(bufB, W2, dinv, bufA, N);
    k_agg<<<gRow8, THREADS, 0, stream>>>(bufA, rowptr, csr, dinv, b2, bufB, N);

    // ---- head ----
    k_out<<<gRow4, THREADS, 0, stream>>>(bufB, Wo, bo, out, N);
}

// Round 6
// 242.360 us; speedup vs baseline: 6.2776x; 1.3226x over previous
//
#include <hip/hip_runtime.h>

#define THREADS 256
#define CHUNK 4096   // edges per k_hist / k_binA block

// ---------------- CSR build: counting sort by dst>>8, then per-bucket -------
__global__ __launch_bounds__(256)
void k_zero(int* __restrict__ bcnt) { bcnt[threadIdx.x] = 0; }

// histogram of dst>>8 over 256 buckets
__global__ __launch_bounds__(256)
void k_hist(const int* __restrict__ dst, int E, int* __restrict__ bcnt) {
    __shared__ int h[256];
    int tid = threadIdx.x;
    h[tid] = 0;
    __syncthreads();
    int base = blockIdx.x * CHUNK;
    #pragma unroll
    for (int i = 0; i < 4; ++i) {
        int e = base + i * 1024 + tid * 4;
        if (e + 3 < E) {
            int4 d4 = *reinterpret_cast<const int4*>(dst + e);
            atomicAdd(&h[d4.x >> 8], 1);
            atomicAdd(&h[d4.y >> 8], 1);
            atomicAdd(&h[d4.z >> 8], 1);
            atomicAdd(&h[d4.w >> 8], 1);
        } else {
            for (int k = e; k < E && k < e + 4; ++k) atomicAdd(&h[dst[k] >> 8], 1);
        }
    }
    __syncthreads();
    if (h[tid]) atomicAdd(&bcnt[tid], h[tid]);
}

// single block: bbase = exclusive scan of bcnt; cursor = copy
__global__ __launch_bounds__(256)
void k_bscan(const int* __restrict__ bcnt, int* __restrict__ bbase, int* __restrict__ cursor) {
    __shared__ int s[256];
    int tid = threadIdx.x;
    s[tid] = bcnt[tid];
    __syncthreads();
    for (int off = 1; off < 256; off <<= 1) {
        int v = (tid >= off) ? s[tid - off] : 0;
        __syncthreads();
        s[tid] += v;
        __syncthreads();
    }
    int excl = (tid == 0) ? 0 : s[tid - 1];
    bbase[tid] = excl;
    cursor[tid] = excl;
}

// bin edges (packed dst<<16|src) into bucket-grouped runs; coalesced writes
__global__ __launch_bounds__(256)
void k_binA(const int* __restrict__ src, const int* __restrict__ dst,
            int* __restrict__ cursor, unsigned int* __restrict__ binned, int E) {
    __shared__ int h[256];
    __shared__ int lbase[256];
    __shared__ int lcur[256];
    __shared__ int gbase[256];
    __shared__ unsigned int stage[CHUNK];
    int tid = threadIdx.x;
    h[tid] = 0;
    __syncthreads();
    int base = blockIdx.x * CHUNK;
    unsigned int pk[16];
    unsigned int mask = 0;
    #pragma unroll
    for (int i = 0; i < 4; ++i) {
        int e = base + i * 1024 + tid * 4;
        if (e + 3 < E) {
            int4 d4 = *reinterpret_cast<const int4*>(dst + e);
            int4 s4 = *reinterpret_cast<const int4*>(src + e);
            pk[i*4+0] = ((unsigned)d4.x << 16) | (unsigned)s4.x; atomicAdd(&h[d4.x >> 8], 1);
            pk[i*4+1] = ((unsigned)d4.y << 16) | (unsigned)s4.y; atomicAdd(&h[d4.y >> 8], 1);
            pk[i*4+2] = ((unsigned)d4.z << 16) | (unsigned)s4.z; atomicAdd(&h[d4.z >> 8], 1);
            pk[i*4+3] = ((unsigned)d4.w << 16) | (unsigned)s4.w; atomicAdd(&h[d4.w >> 8], 1);
            mask |= 0xFu << (i * 4);
        } else {
            for (int j = 0; j < 4; ++j) {
                int k = e + j;
                if (k < E) {
                    int d = dst[k], s = src[k];
                    pk[i*4+j] = ((unsigned)d << 16) | (unsigned)s;
                    atomicAdd(&h[d >> 8], 1);
                    mask |= 1u << (i * 4 + j);
                }
            }
        }
    }
    __syncthreads();
    // inclusive scan of h
    for (int off = 1; off < 256; off <<= 1) {
        int v = (tid >= off) ? h[tid - off] : 0;
        __syncthreads();
        h[tid] += v;
        __syncthreads();
    }
    int incl = h[tid];
    int excl = (tid == 0) ? 0 : h[tid - 1];
    int cntb = incl - excl;
    lbase[tid] = excl;
    lcur[tid] = excl;
    gbase[tid] = cntb ? atomicAdd(&cursor[tid], cntb) : 0;
    __syncthreads();
    int nvalid = h[255];
    #pragma unroll
    for (int i = 0; i < 16; ++i) {
        if (mask & (1u << i)) {
            int b = pk[i] >> 24;
            int p = atomicAdd(&lcur[b], 1);
            stage[p] = pk[i];
        }
    }
    __syncthreads();
    for (int i = tid; i < nvalid; i += 256) {
        unsigned int v = stage[i];
        int b = v >> 24;
        binned[gbase[b] + (i - lbase[b])] = v;
    }
}

// one block per bucket (256 nodes): per-node count, scan -> rowptr/dinv,
// self entry inserted first in each row, then edges, in block-OWNED region.
// csr has E+N entries total; rowptr[N] = E+N.
__global__ __launch_bounds__(256)
void k_binB(const unsigned int* __restrict__ binned, const int* __restrict__ bbase,
            int* __restrict__ rowptr, float* __restrict__ dinv,
            unsigned short* __restrict__ csr, int N, int EN) {
    __shared__ int cnt[256];
    __shared__ int lcur[256];
    int tid = threadIdx.x;
    int b = blockIdx.x;
    int bb0 = bbase[b];
    int bb1 = bbase[b + 1];
    int csrbase = bb0 + (b << 8);   // bucket region start incl. self entries
    cnt[tid] = 0;
    __syncthreads();
    for (int i = bb0 + tid; i < bb1; i += 256) {
        atomicAdd(&cnt[(binned[i] >> 16) & 255], 1);
    }
    __syncthreads();
    int myc = cnt[tid];
    __syncthreads();
    for (int off = 1; off < 256; off <<= 1) {
        int v = (tid >= off) ? cnt[tid - off] : 0;
        __syncthreads();
        cnt[tid] += v;
        __syncthreads();
    }
    int excl = cnt[tid] - myc;
    int node = (b << 8) + tid;
    int roff = excl + tid;          // relative row start (self entries of prior nodes)
    if (node < N) {
        rowptr[node] = csrbase + roff;
        dinv[node] = rsqrtf((float)(myc + 1));   // +1 self loop
        csr[csrbase + roff] = (unsigned short)node;   // self entry first
    }
    if (b == 0 && tid == 0) rowptr[N] = EN;
    lcur[tid] = roff + 1;
    __syncthreads();
    for (int i = bb0 + tid; i < bb1; i += 256) {
        unsigned int v = binned[i];
        int dl = (v >> 16) & 255;
        int p = atomicAdd(&lcur[dl], 1);
        csr[csrbase + p] = (unsigned short)(v & 0xFFFFu);
    }
}

// ---------------- dense transforms (epilogue: scale row by dinv) ----------
__global__ __launch_bounds__(THREADS)
void k_gemm1(const float* __restrict__ x, const float* __restrict__ W,
             const float* __restrict__ dinv, float* __restrict__ hp, int N) {
    __shared__ float Ws[128 * 32];
    __shared__ float xs[8][128];
    int tid = threadIdx.x;
    for (int j = tid; j < 128 * 32; j += THREADS) Ws[j] = W[j];
    int row0 = blockIdx.x * 8;
    if (row0 + 8 <= N) {
        const float4* xv = reinterpret_cast<const float4*>(x + (size_t)row0 * 128);
        float4 u = xv[tid];
        int base = tid * 4;
        int r = base >> 7, k = base & 127;
        xs[r][k + 0] = u.x; xs[r][k + 1] = u.y;
        xs[r][k + 2] = u.z; xs[r][k + 3] = u.w;
    } else {
        for (int j = tid; j < 8 * 128; j += THREADS) {
            int r = j >> 7, k = j & 127;
            int gr = row0 + r;
            xs[r][k] = (gr < N) ? x[(size_t)gr * 128 + k] : 0.f;
        }
    }
    __syncthreads();
    int r = tid >> 5, c = tid & 31;
    int grow = row0 + r;
    if (grow < N) {
        float acc = 0.f;
        #pragma unroll
        for (int k = 0; k < 128; ++k) acc += xs[r][k] * Ws[k * 32 + c];
        hp[(size_t)grow * 32 + c] = acc * dinv[grow];
    }
}

__global__ __launch_bounds__(THREADS)
void k_gemm2(const float* __restrict__ hin, const float* __restrict__ W,
             const float* __restrict__ dinv, float* __restrict__ hp, int N) {
    __shared__ float Ws[32 * 32];
    __shared__ float xs[8][32];
    int tid = threadIdx.x;
    for (int j = tid; j < 1024; j += THREADS) Ws[j] = W[j];
    int row0 = blockIdx.x * 8;
    for (int j = tid; j < 256; j += THREADS) {
        int r = j >> 5, k = j & 31;
        int gr = row0 + r;
        xs[r][k] = (gr < N) ? hin[(size_t)gr * 32 + k] : 0.f;
    }
    __syncthreads();
    int r = tid >> 5, c = tid & 31;
    int gr = row0 + r;
    if (gr < N) {
        float acc = 0.f;
        #pragma unroll
        for (int k = 0; k < 32; ++k) acc += xs[r][k] * Ws[k * 32 + c];
        hp[(size_t)gr * 32 + c] = acc * dinv[gr];
    }
}

__global__ __launch_bounds__(THREADS)
void k_out(const float* __restrict__ hin, const float* __restrict__ W,
           const float* __restrict__ b, float* __restrict__ out, int N) {
    __shared__ float Ws[32 * 64];
    __shared__ float bs[64];
    __shared__ float xs[4][32];
    int tid = threadIdx.x;
    for (int j = tid; j < 2048; j += THREADS) Ws[j] = W[j];
    if (tid < 64) bs[tid] = b[tid];
    int row0 = blockIdx.x * 4;
    if (tid < 128) {
        int r = tid >> 5, k = tid & 31;
        int gr = row0 + r;
        xs[r][k] = (gr < N) ? hin[(size_t)gr * 32 + k] : 0.f;
    }
    __syncthreads();
    int r = tid >> 6, c = tid & 63;
    int gr = row0 + r;
    if (gr < N) {
        float acc = bs[c];
        #pragma unroll
        for (int k = 0; k < 32; ++k) acc += xs[r][k] * Ws[k * 64 + c];
        out[(size_t)gr * 64 + c] = acc;
    }
}

// ---------------- aggregation: 1 wave per node, 8 rows per load -------------
// lane = j*8+q: j = row slot (8 rows gathered per iteration), q = feature quad.
// csr rows include the self entry; hp rows pre-scaled by dinv[row].
__global__ __launch_bounds__(THREADS)
void k_agg(const float* __restrict__ hp, const int* __restrict__ rowptr,
           const unsigned short* __restrict__ csr, const float* __restrict__ dinv,
           const float* __restrict__ b, float* __restrict__ out, int N) {
    int lane = threadIdx.x & 63;
    int node = blockIdx.x * 4 + (threadIdx.x >> 6);
    int j = lane >> 3;   // 0..7 row slot
    int q = lane & 7;    // 0..7 feature quad
    int beg = rowptr[node];
    int end = rowptr[node + 1];
    float4 acc = make_float4(0.f, 0.f, 0.f, 0.f);
    for (int base = beg; base < end; base += 64) {
        int idx = base + lane;
        int cv = (idx < end) ? (int)csr[idx] : 0;
        int nin = end - base; if (nin > 64) nin = 64;
        for (int c = 0; c < nin; c += 8) {
            int s = __shfl(cv, c + j, 64);
            if (c + j < nin) {
                const float4 v = *reinterpret_cast<const float4*>(hp + (size_t)s * 32 + q * 4);
                acc.x += v.x; acc.y += v.y; acc.z += v.z; acc.w += v.w;
            }
        }
    }
    #pragma unroll
    for (int d = 8; d < 64; d <<= 1) {
        acc.x += __shfl_xor(acc.x, d, 64);
        acc.y += __shfl_xor(acc.y, d, 64);
        acc.z += __shfl_xor(acc.z, d, 64);
        acc.w += __shfl_xor(acc.w, d, 64);
    }
    if (lane < 8) {
        float dd = dinv[node];
        const float4 bv = *reinterpret_cast<const float4*>(b + q * 4);
        float4 o;
        o.x = fmaxf(acc.x * dd + bv.x, 0.f);
        o.y = fmaxf(acc.y * dd + bv.y, 0.f);
        o.z = fmaxf(acc.z * dd + bv.z, 0.f);
        o.w = fmaxf(acc.w * dd + bv.w, 0.f);
        *reinterpret_cast<float4*>(out + (size_t)node * 32 + q * 4) = o;
    }
}

extern "C" void kernel_launch(void* const* d_in, const int* in_sizes, int n_in,
                              void* d_out, int out_size, void* d_ws, size_t ws_size,
                              hipStream_t stream) {
    const float* x  = (const float*)d_in[0];
    const int*   ei = (const int*)d_in[1];
    const float* W1 = (const float*)d_in[2];
    const float* b1 = (const float*)d_in[3];
    const float* W2 = (const float*)d_in[4];
    const float* b2 = (const float*)d_in[5];
    const float* Wo = (const float*)d_in[6];
    const float* bo = (const float*)d_in[7];
    float* out = (float*)d_out;

    const int N = in_sizes[0] / 128;   // 50000
    const int E = in_sizes[1] / 2;     // 1600000
    const int N32 = N * 32;
    const int* src = ei;
    const int* dst = ei + E;

    char* ws = (char*)d_ws;
    size_t off = 0;
    auto alloc = [&](size_t bytes) {
        void* p = ws + off;
        off += (bytes + 255) & ~(size_t)255;
        return p;
    };
    int*            bcnt   = (int*)           alloc(256 * 4);
    int*            bbase  = (int*)           alloc(256 * 4);
    int*            cursor = (int*)           alloc(256 * 4);
    unsigned int*   binned = (unsigned int*)  alloc((size_t)E * 4);
    int*            rowptr = (int*)           alloc((size_t)(N + 1) * 4);
    float*          dinv   = (float*)         alloc((size_t)N * 4);
    unsigned short* csr    = (unsigned short*)alloc((size_t)(E + N) * 2);
    float*          bufA   = (float*)         alloc((size_t)N32 * 4);
    float*          bufB   = (float*)         alloc((size_t)N32 * 4);

    const int gRow8  = (N + 7) / 8;
    const int gRow4  = (N + 3) / 4;
    const int gChunk = (E + CHUNK - 1) / CHUNK;      // 391
    const int nBuckets = (N + 255) >> 8;             // 196

    // ---- CSR build (counting sort by dst>>8; block-owned scatter) ----
    k_zero<<<1, 256, 0, stream>>>(bcnt);
    k_hist<<<gChunk, 256, 0, stream>>>(dst, E, bcnt);
    k_bscan<<<1, 256, 0, stream>>>(bcnt, bbase, cursor);
    k_binA<<<gChunk, 256, 0, stream>>>(src, dst, cursor, binned, E);
    k_binB<<<nBuckets, 256, 0, stream>>>(binned, bbase, rowptr, dinv, csr, N, E + N);

    // ---- layer 1 ----
    k_gemm1<<<gRow8, THREADS, 0, stream>>>(x, W1, dinv, bufA, N);
    k_agg<<<gRow4, THREADS, 0, stream>>>(bufA, rowptr, csr, dinv, b1, bufB, N);

    // ---- layer 2 ----
    k_gemm2<<<gRow8, THREADS, 0, stream>>>(bufB, W2, dinv, bufA, N);
    k_agg<<<gRow4, THREADS, 0, stream>>>(bufA, rowptr, csr, dinv, b2, bufB, N);

    // ---- head ----
    k_out<<<gRow4, THREADS, 0, stream>>>(bufB, Wo, bo, out, N);
}

// Round 7
// 238.706 us; speedup vs baseline: 6.3737x; 1.0153x over previous
//
#include <hip/hip_runtime.h>

#define THREADS 256
#define CHUNK 4096        // edges per binA block
#define BCAP  16384       // per-bucket edge capacity (mean 8163, 91 sigma slack)
#define CCAP  (BCAP+256)  // csr region capacity (edges + self entries)

__global__ __launch_bounds__(256)
void k_init_cursor(int* __restrict__ cursor) {
    cursor[threadIdx.x] = threadIdx.x * BCAP;
}

// mega1: blocks [0,nbinA) bin edges into bucket regions; rest compute h = x@W1 (unscaled)
__global__ __launch_bounds__(256)
void k_mega1(const int* __restrict__ src, const int* __restrict__ dst, int E,
             int* __restrict__ cursor, unsigned int* __restrict__ binned,
             const float* __restrict__ x, const float* __restrict__ W,
             float* __restrict__ h, int N, int nbinA) {
    __shared__ int cnt[256];
    __shared__ int gbs[256];
    __shared__ float xs[256][33];
    __shared__ float Wsh[4096];
    int tid = threadIdx.x;
    if ((int)blockIdx.x < nbinA) {
        // ---------- binA: rank + reserve + direct scatter ----------
        cnt[tid] = 0;
        __syncthreads();
        int base = blockIdx.x * CHUNK;
        unsigned int pk[16];
        int rk[16];
        unsigned int mask = 0;
        #pragma unroll
        for (int i = 0; i < 4; ++i) {
            int e = base + i * 1024 + tid * 4;
            if (e + 3 < E) {
                int4 d4 = *reinterpret_cast<const int4*>(dst + e);
                int4 s4 = *reinterpret_cast<const int4*>(src + e);
                pk[i*4+0] = ((unsigned)d4.x << 16) | (unsigned)s4.x; rk[i*4+0] = atomicAdd(&cnt[d4.x >> 8], 1);
                pk[i*4+1] = ((unsigned)d4.y << 16) | (unsigned)s4.y; rk[i*4+1] = atomicAdd(&cnt[d4.y >> 8], 1);
                pk[i*4+2] = ((unsigned)d4.z << 16) | (unsigned)s4.z; rk[i*4+2] = atomicAdd(&cnt[d4.z >> 8], 1);
                pk[i*4+3] = ((unsigned)d4.w << 16) | (unsigned)s4.w; rk[i*4+3] = atomicAdd(&cnt[d4.w >> 8], 1);
                mask |= 0xFu << (i * 4);
            } else {
                for (int j = 0; j < 4; ++j) {
                    int k = e + j;
                    if (k < E) {
                        int d = dst[k], s = src[k];
                        pk[i*4+j] = ((unsigned)d << 16) | (unsigned)s;
                        rk[i*4+j] = atomicAdd(&cnt[d >> 8], 1);
                        mask |= 1u << (i * 4 + j);
                    }
                }
            }
        }
        __syncthreads();
        int c = cnt[tid];
        gbs[tid] = c ? atomicAdd(&cursor[tid], c) : 0;
        __syncthreads();
        #pragma unroll
        for (int i = 0; i < 16; ++i) {
            if (mask & (1u << i)) {
                int b = pk[i] >> 24;
                binned[gbs[b] + rk[i]] = pk[i];
            }
        }
    } else {
        // ---------- gemm1: h[row][0..31] = x[row][:] @ W, acc[32]/thread ----------
        int row0 = ((int)blockIdx.x - nbinA) * 256;
        for (int j = tid; j < 1024; j += 256)
            reinterpret_cast<float4*>(Wsh)[j] = reinterpret_cast<const float4*>(W)[j];
        float acc[32];
        #pragma unroll
        for (int q = 0; q < 32; ++q) acc[q] = 0.f;
        for (int kc = 0; kc < 128; kc += 32) {
            __syncthreads();
            #pragma unroll
            for (int i = 0; i < 8; ++i) {
                int flat = i * 256 + tid;
                int a = flat >> 3, bq = flat & 7;
                int row = row0 + a;
                float4 v = (row < N)
                    ? *reinterpret_cast<const float4*>(x + (size_t)row * 128 + kc + bq * 4)
                    : make_float4(0.f, 0.f, 0.f, 0.f);
                xs[a][bq*4+0] = v.x; xs[a][bq*4+1] = v.y;
                xs[a][bq*4+2] = v.z; xs[a][bq*4+3] = v.w;
            }
            __syncthreads();
            #pragma unroll
            for (int k = 0; k < 32; ++k) {
                float xv = xs[tid][k];
                const float4* wr = reinterpret_cast<const float4*>(Wsh + (kc + k) * 32);
                #pragma unroll
                for (int q = 0; q < 8; ++q) {
                    float4 w = wr[q];
                    acc[q*4+0] += xv * w.x; acc[q*4+1] += xv * w.y;
                    acc[q*4+2] += xv * w.z; acc[q*4+3] += xv * w.w;
                }
            }
        }
        int row = row0 + tid;
        if (row < N) {
            float4* o = reinterpret_cast<float4*>(h + (size_t)row * 32);
            #pragma unroll
            for (int q = 0; q < 8; ++q)
                o[q] = make_float4(acc[q*4], acc[q*4+1], acc[q*4+2], acc[q*4+3]);
        }
    }
}

// binB: per-bucket node counts -> rowbeg/rowend/dinv/csr (self entry first),
// then scale h rows by dinv in place.
__global__ __launch_bounds__(256)
void k_binB(const unsigned int* __restrict__ binned, const int* __restrict__ cursor,
            int* __restrict__ rowbeg, int* __restrict__ rowend, float* __restrict__ dinvg,
            unsigned short* __restrict__ csr, float* __restrict__ h, int N) {
    __shared__ int cnt[256];
    __shared__ int sc[256];
    __shared__ int lcur[256];
    __shared__ float dv[256];
    int tid = threadIdx.x;
    int b = blockIdx.x;
    int ebase = b * BCAP;
    int ne = cursor[b] - ebase;
    cnt[tid] = 0;
    __syncthreads();
    for (int i = tid; i < ne; i += 256)
        atomicAdd(&cnt[(binned[ebase + i] >> 16) & 255], 1);
    __syncthreads();
    int myc = cnt[tid];
    sc[tid] = myc;
    __syncthreads();
    for (int off = 1; off < 256; off <<= 1) {
        int v = (tid >= off) ? sc[tid - off] : 0;
        __syncthreads();
        sc[tid] += v;
        __syncthreads();
    }
    int excl = sc[tid] - myc;
    int node = (b << 8) + tid;
    int cbase = b * CCAP;
    int rb = cbase + excl + tid;
    float di = rsqrtf((float)(myc + 1));
    dv[tid] = di;
    if (node < N) {
        rowbeg[node] = rb;
        rowend[node] = rb + 1 + myc;
        dinvg[node] = di;
        csr[rb] = (unsigned short)node;   // self entry first
    }
    lcur[tid] = excl + tid + 1;
    __syncthreads();
    for (int i = tid; i < ne; i += 256) {
        unsigned int v = binned[ebase + i];
        int nl = (v >> 16) & 255;
        int p = atomicAdd(&lcur[nl], 1);
        csr[cbase + p] = (unsigned short)(v & 0xFFFFu);
    }
    // scale owned h rows by dinv (in place)
    __syncthreads();
    float4* h4 = reinterpret_cast<float4*>(h);
    size_t h4base = (size_t)(b << 8) * 8;
    for (int j = tid; j < 2048; j += 256) {
        int nl = j >> 3;
        if (((b << 8) + nl) < N) {
            float4 v = h4[h4base + j];
            float d = dv[nl];
            v.x *= d; v.y *= d; v.z *= d; v.w *= d;
            h4[h4base + j] = v;
        }
    }
}

// gemm2: hp[N,32] = (hin[N,32] @ W[32,32]) * dinv[row]
__global__ __launch_bounds__(THREADS)
void k_gemm2(const float* __restrict__ hin, const float* __restrict__ W,
             const float* __restrict__ dinv, float* __restrict__ hp, int N) {
    __shared__ float Ws[32 * 32];
    __shared__ float xs[8][32];
    int tid = threadIdx.x;
    for (int j = tid; j < 1024; j += THREADS) Ws[j] = W[j];
    int row0 = blockIdx.x * 8;
    for (int j = tid; j < 256; j += THREADS) {
        int r = j >> 5, k = j & 31;
        int gr = row0 + r;
        xs[r][k] = (gr < N) ? hin[(size_t)gr * 32 + k] : 0.f;
    }
    __syncthreads();
    int r = tid >> 5, c = tid & 31;
    int gr = row0 + r;
    if (gr < N) {
        float acc = 0.f;
        #pragma unroll
        for (int k = 0; k < 32; ++k) acc += xs[r][k] * Ws[k * 32 + c];
        hp[(size_t)gr * 32 + c] = acc * dinv[gr];
    }
}

__global__ __launch_bounds__(THREADS)
void k_out(const float* __restrict__ hin, const float* __restrict__ W,
           const float* __restrict__ b, float* __restrict__ out, int N) {
    __shared__ float Ws[32 * 64];
    __shared__ float bs[64];
    __shared__ float xs[4][32];
    int tid = threadIdx.x;
    for (int j = tid; j < 2048; j += THREADS) Ws[j] = W[j];
    if (tid < 64) bs[tid] = b[tid];
    int row0 = blockIdx.x * 4;
    if (tid < 128) {
        int r = tid >> 5, k = tid & 31;
        int gr = row0 + r;
        xs[r][k] = (gr < N) ? hin[(size_t)gr * 32 + k] : 0.f;
    }
    __syncthreads();
    int r = tid >> 6, c = tid & 63;
    int gr = row0 + r;
    if (gr < N) {
        float acc = bs[c];
        #pragma unroll
        for (int k = 0; k < 32; ++k) acc += xs[r][k] * Ws[k * 64 + c];
        out[(size_t)gr * 64 + c] = acc;
    }
}

// aggregation: 1 wave per node, 8 rows per float4-gather, shfl reduce
__global__ __launch_bounds__(THREADS)
void k_agg(const float* __restrict__ hp, const int* __restrict__ rowbeg,
           const int* __restrict__ rowend, const unsigned short* __restrict__ csr,
           const float* __restrict__ dinv, const float* __restrict__ b,
           float* __restrict__ out, int N) {
    int lane = threadIdx.x & 63;
    int node = blockIdx.x * 4 + (threadIdx.x >> 6);
    int j = lane >> 3;   // row slot
    int q = lane & 7;    // feature quad
    int beg = rowbeg[node];
    int end = rowend[node];
    float4 acc = make_float4(0.f, 0.f, 0.f, 0.f);
    for (int base = beg; base < end; base += 64) {
        int idx = base + lane;
        int cv = (idx < end) ? (int)csr[idx] : 0;
        int nin = end - base; if (nin > 64) nin = 64;
        for (int c = 0; c < nin; c += 8) {
            int s = __shfl(cv, c + j, 64);
            if (c + j < nin) {
                const float4 v = *reinterpret_cast<const float4*>(hp + (size_t)s * 32 + q * 4);
                acc.x += v.x; acc.y += v.y; acc.z += v.z; acc.w += v.w;
            }
        }
    }
    #pragma unroll
    for (int d = 8; d < 64; d <<= 1) {
        acc.x += __shfl_xor(acc.x, d, 64);
        acc.y += __shfl_xor(acc.y, d, 64);
        acc.z += __shfl_xor(acc.z, d, 64);
        acc.w += __shfl_xor(acc.w, d, 64);
    }
    if (lane < 8) {
        float dd = dinv[node];
        const float4 bv = *reinterpret_cast<const float4*>(b + q * 4);
        float4 o;
        o.x = fmaxf(acc.x * dd + bv.x, 0.f);
        o.y = fmaxf(acc.y * dd + bv.y, 0.f);
        o.z = fmaxf(acc.z * dd + bv.z, 0.f);
        o.w = fmaxf(acc.w * dd + bv.w, 0.f);
        *reinterpret_cast<float4*>(out + (size_t)node * 32 + q * 4) = o;
    }
}

extern "C" void kernel_launch(void* const* d_in, const int* in_sizes, int n_in,
                              void* d_out, int out_size, void* d_ws, size_t ws_size,
                              hipStream_t stream) {
    const float* x  = (const float*)d_in[0];
    const int*   ei = (const int*)d_in[1];
    const float* W1 = (const float*)d_in[2];
    const float* b1 = (const float*)d_in[3];
    const float* W2 = (const float*)d_in[4];
    const float* b2 = (const float*)d_in[5];
    const float* Wo = (const float*)d_in[6];
    const float* bo = (const float*)d_in[7];
    float* out = (float*)d_out;

    const int N = in_sizes[0] / 128;   // 50000
    const int E = in_sizes[1] / 2;     // 1600000
    const int N32 = N * 32;
    const int* src = ei;
    const int* dst = ei + E;

    char* ws = (char*)d_ws;
    size_t off = 0;
    auto alloc = [&](size_t bytes) {
        void* p = ws + off;
        off += (bytes + 255) & ~(size_t)255;
        return p;
    };
    const int nBuckets = (N + 255) >> 8;             // 196
    int*            cursor = (int*)           alloc(256 * 4);
    unsigned int*   binned = (unsigned int*)  alloc((size_t)nBuckets * BCAP * 4);
    int*            rowbeg = (int*)           alloc((size_t)N * 4);
    int*            rowend = (int*)           alloc((size_t)N * 4);
    float*          dinv   = (float*)         alloc((size_t)N * 4);
    unsigned short* csr    = (unsigned short*)alloc((size_t)nBuckets * CCAP * 2);
    float*          bufA   = (float*)         alloc((size_t)N32 * 4);
    float*          bufB   = (float*)         alloc((size_t)N32 * 4);

    const int gRow8  = (N + 7) / 8;                  // 6250
    const int gRow4  = (N + 3) / 4;                  // 12500
    const int nbinA  = (E + CHUNK - 1) / CHUNK;      // 391
    const int nGemm1 = (N + 255) / 256;              // 196

    // build (binA) runs concurrently with layer-1 transform (gemm1, unscaled)
    k_init_cursor<<<1, 256, 0, stream>>>(cursor);
    k_mega1<<<nbinA + nGemm1, 256, 0, stream>>>(src, dst, E, cursor, binned,
                                                x, W1, bufA, N, nbinA);
    k_binB<<<nBuckets, 256, 0, stream>>>(binned, cursor, rowbeg, rowend, dinv,
                                         csr, bufA, N);

    // layer 1 aggregate (+bias+relu)
    k_agg<<<gRow4, THREADS, 0, stream>>>(bufA, rowbeg, rowend, csr, dinv, b1, bufB, N);

    // layer 2
    k_gemm2<<<gRow8, THREADS, 0, stream>>>(bufB, W2, dinv, bufA, N);
    k_agg<<<gRow4, THREADS, 0, stream>>>(bufA, rowbeg, rowend, csr, dinv, b2, bufB, N);

    // head
    k_out<<<gRow4, THREADS, 0, stream>>>(bufB, Wo, bo, out, N);
}